// Round 2
// baseline (1999.330 us; speedup 1.0000x reference)
//
#include <hip/hip_runtime.h>
#include <hip/hip_bf16.h>
#include <math.h>

constexpr int B_N   = 32;
constexpr int L_N   = 4096;     // H*W
constexpr int DM    = 256;
constexpr int DIN   = 512;
constexpr int DS    = 64;
constexpr int NH    = 8;
constexpr int HD    = 64;
constexpr int NPROJ = 648;      // 512 + 64 + 64 + 8
constexpr int M_N   = B_N * L_N; // 131072

__device__ __forceinline__ float softplusf(float z) {
  return (z > 20.f) ? z : log1pf(expf(z));
}

// ---------- Kernel 1: xbcdt = u @ W_in, fused dt -> dA ----------
__global__ __launch_bounds__(256) void k_inproj(
    const float* __restrict__ u, const float* __restrict__ Wi,
    const float* __restrict__ dt_bias, const float* __restrict__ A_log,
    float* __restrict__ xbcdt) {
  __shared__ float sAT[32][65];
  __shared__ float sB[32][64];
  const int n0 = blockIdx.x * 64;
  const int m0 = blockIdx.y * 64;
  const int tid = threadIdx.x;
  const int tr = tid >> 4, tc = tid & 15;
  float acc[4][4] = {};
  for (int k0 = 0; k0 < DM; k0 += 32) {
    __syncthreads();
    // stage A (64 rows x 32 k), transposed into LDS
#pragma unroll
    for (int q = 0; q < 2; ++q) {
      int s = tid + q * 256;            // 512 float4 slots
      int row = s >> 3, f4 = s & 7;
      float4 v = *reinterpret_cast<const float4*>(u + (size_t)(m0 + row) * DM + k0 + f4 * 4);
      sAT[f4 * 4 + 0][row] = v.x; sAT[f4 * 4 + 1][row] = v.y;
      sAT[f4 * 4 + 2][row] = v.z; sAT[f4 * 4 + 3][row] = v.w;
    }
    // stage B (32 k x 64 n), bounds-checked on N=648
#pragma unroll
    for (int q = 0; q < 2; ++q) {
      int s = tid + q * 256;
      int kr = s >> 4, f4 = s & 15;
      int col = n0 + f4 * 4;
      float4 v = make_float4(0.f, 0.f, 0.f, 0.f);
      if (col + 4 <= NPROJ)
        v = *reinterpret_cast<const float4*>(Wi + (size_t)(k0 + kr) * NPROJ + col);
      sB[kr][f4 * 4 + 0] = v.x; sB[kr][f4 * 4 + 1] = v.y;
      sB[kr][f4 * 4 + 2] = v.z; sB[kr][f4 * 4 + 3] = v.w;
    }
    __syncthreads();
#pragma unroll
    for (int kk = 0; kk < 32; ++kk) {
      float a[4], b[4];
#pragma unroll
      for (int i = 0; i < 4; ++i) a[i] = sAT[kk][tr * 4 + i];
#pragma unroll
      for (int j = 0; j < 4; ++j) b[j] = sB[kk][tc * 4 + j];
#pragma unroll
      for (int i = 0; i < 4; ++i)
#pragma unroll
        for (int j = 0; j < 4; ++j) acc[i][j] += a[i] * b[j];
    }
  }
#pragma unroll
  for (int i = 0; i < 4; ++i) {
    int row = m0 + tr * 4 + i;
#pragma unroll
    for (int j = 0; j < 4; ++j) {
      int col = n0 + tc * 4 + j;
      if (col < DIN + 2 * DS) {
        xbcdt[(size_t)row * NPROJ + col] = acc[i][j];
      } else if (col < NPROJ) {
        int h = col - (DIN + 2 * DS);
        float dt = softplusf(acc[i][j] + dt_bias[h]);
        xbcdt[(size_t)row * NPROJ + col] = dt * (-expf(A_log[h]));
      }
    }
  }
}

// ---------- Kernel 2: KV[b,h,s,p] = sum_l B[l,s] * V[l,h,p] * dA[l,h] ----------
__global__ __launch_bounds__(256) void k_kv(
    const float* __restrict__ xbcdt, float* __restrict__ KV) {
  const int bh = blockIdx.y;           // b*8 + h
  const int b = bh >> 3, h = bh & 7;
  const int l0 = blockIdx.x * (L_N / 8);
  const int tid = threadIdx.x;
  __shared__ float sB[8][64];
  __shared__ float sV[8][64];
  __shared__ float sdA[8];
  const int s_idx = tid >> 2;
  const int p0 = (tid & 3) * 16;
  float acc[16] = {};
  for (int lt = 0; lt < L_N / 8; lt += 8) {
    __syncthreads();
    if (tid < 128) {
      int row = tid >> 4, f4 = tid & 15;
      size_t gr = (size_t)(b * L_N + l0 + lt + row) * NPROJ;
      float4 v = *reinterpret_cast<const float4*>(xbcdt + gr + DIN + f4 * 4);
      sB[row][f4 * 4 + 0] = v.x; sB[row][f4 * 4 + 1] = v.y;
      sB[row][f4 * 4 + 2] = v.z; sB[row][f4 * 4 + 3] = v.w;
    } else {
      int t = tid - 128;
      int row = t >> 4, f4 = t & 15;
      size_t gr = (size_t)(b * L_N + l0 + lt + row) * NPROJ;
      float4 v = *reinterpret_cast<const float4*>(xbcdt + gr + h * HD + f4 * 4);
      sV[row][f4 * 4 + 0] = v.x; sV[row][f4 * 4 + 1] = v.y;
      sV[row][f4 * 4 + 2] = v.z; sV[row][f4 * 4 + 3] = v.w;
    }
    if (tid < 8)
      sdA[tid] = xbcdt[(size_t)(b * L_N + l0 + lt + tid) * NPROJ + DIN + 2 * DS + h];
    __syncthreads();
#pragma unroll
    for (int i = 0; i < 8; ++i) {
      float w = sB[i][s_idx] * sdA[i];
#pragma unroll
      for (int j = 0; j < 16; ++j) acc[j] += w * sV[i][p0 + j];
    }
  }
  float* dst = KV + ((size_t)bh * 64 + s_idx) * 64 + p0;
#pragma unroll
  for (int j = 0; j < 16; ++j) atomicAdd(dst + j, acc[j]);
}

// ---------- Kernel 3: y = C @ KV(+) + V*D, stored in-place over x_ssm ----------
__global__ __launch_bounds__(256) void k_ygemm(
    float* __restrict__ xbcdt, const float* __restrict__ KV,
    const float* __restrict__ D_param) {
  __shared__ float sCT[64][65];
  __shared__ float sW[64][64];
  const int n0 = blockIdx.x * 64;      // within DIN
  const int m0 = blockIdx.y * 64;
  const int b = m0 >> 12;              // 4096 rows per batch
  const int h = n0 >> 6;
  const int tid = threadIdx.x;
  const int tr = tid >> 4, tc = tid & 15;
#pragma unroll
  for (int q = 0; q < 4; ++q) {        // stage C^T: 64 rows x 64 s = 1024 float4
    int s = tid + q * 256;
    int row = s >> 4, f4 = s & 15;
    float4 v = *reinterpret_cast<const float4*>(xbcdt + (size_t)(m0 + row) * NPROJ + DIN + DS + f4 * 4);
    sCT[f4 * 4 + 0][row] = v.x; sCT[f4 * 4 + 1][row] = v.y;
    sCT[f4 * 4 + 2][row] = v.z; sCT[f4 * 4 + 3][row] = v.w;
  }
  {
    const float* kvb = KV + (size_t)(b * NH + h) * 64 * 64;
#pragma unroll
    for (int q = 0; q < 4; ++q) {      // stage KV tile 64x64
      int s = tid + q * 256;
      int sr = s >> 4, f4 = s & 15;
      float4 v = *reinterpret_cast<const float4*>(kvb + sr * 64 + f4 * 4);
      sW[sr][f4 * 4 + 0] = v.x; sW[sr][f4 * 4 + 1] = v.y;
      sW[sr][f4 * 4 + 2] = v.z; sW[sr][f4 * 4 + 3] = v.w;
    }
  }
  __syncthreads();
  float acc[4][4] = {};
#pragma unroll
  for (int kk = 0; kk < 64; ++kk) {
    float a[4], bb[4];
#pragma unroll
    for (int i = 0; i < 4; ++i) a[i] = sCT[kk][tr * 4 + i];
#pragma unroll
    for (int j = 0; j < 4; ++j) bb[j] = sW[kk][tc * 4 + j];
#pragma unroll
    for (int i = 0; i < 4; ++i)
#pragma unroll
      for (int j = 0; j < 4; ++j) acc[i][j] += a[i] * bb[j];
  }
  const float dscale = D_param[h];
#pragma unroll
  for (int i = 0; i < 4; ++i) {
    int row = m0 + tr * 4 + i;
#pragma unroll
    for (int j = 0; j < 4; ++j) {
      int col = n0 + tc * 4 + j;
      float v = xbcdt[(size_t)row * NPROJ + col];
      xbcdt[(size_t)row * NPROJ + col] = acc[i][j] + v * dscale;
    }
  }
}

// ---------- Kernel 3b: per-row mean / rstd over the 512 y columns ----------
__global__ __launch_bounds__(256) void k_stats(
    const float* __restrict__ xbcdt, float* __restrict__ mu, float* __restrict__ rstd) {
  const int w = threadIdx.x >> 6, lane = threadIdx.x & 63;
  const int row = blockIdx.x * 4 + w;
  const float* yr = xbcdt + (size_t)row * NPROJ;
  float4 v0 = *reinterpret_cast<const float4*>(yr + lane * 8);
  float4 v1 = *reinterpret_cast<const float4*>(yr + lane * 8 + 4);
  float s = v0.x + v0.y + v0.z + v0.w + v1.x + v1.y + v1.z + v1.w;
  float q = v0.x * v0.x + v0.y * v0.y + v0.z * v0.z + v0.w * v0.w +
            v1.x * v1.x + v1.y * v1.y + v1.z * v1.z + v1.w * v1.w;
#pragma unroll
  for (int off = 32; off > 0; off >>= 1) {
    s += __shfl_down(s, off);
    q += __shfl_down(q, off);
  }
  if (lane == 0) {
    float m = s / DIN;
    mu[row] = m;
    rstd[row] = rsqrtf(q / DIN - m * m + 1e-5f);
  }
}

// ---------- Kernel 4: out = LN(y) @ W_out (LN fused into A staging) ----------
__global__ __launch_bounds__(256) void k_outgemm(
    const float* __restrict__ xbcdt, const float* __restrict__ mu,
    const float* __restrict__ rstd, const float* __restrict__ gamma,
    const float* __restrict__ beta, const float* __restrict__ Wo,
    float* __restrict__ out) {
  __shared__ float sAT[64][65];
  __shared__ float sB[64][64];
  const int n0 = blockIdx.x * 64;
  const int m0 = blockIdx.y * 64;
  const int tid = threadIdx.x;
  const int tr = tid >> 4, tc = tid & 15;
  float acc[4][4] = {};
  for (int k0 = 0; k0 < DIN; k0 += 64) {
    __syncthreads();
#pragma unroll
    for (int q = 0; q < 4; ++q) {      // stage A' = (y-mu)*rstd*gamma+beta, transposed
      int s = tid + q * 256;
      int row = s >> 4, f4 = s & 15;
      int gr = m0 + row;
      float m = mu[gr], r = rstd[gr];
      float4 v = *reinterpret_cast<const float4*>(xbcdt + (size_t)gr * NPROJ + k0 + f4 * 4);
      float4 g = *reinterpret_cast<const float4*>(gamma + k0 + f4 * 4);
      float4 bt = *reinterpret_cast<const float4*>(beta + k0 + f4 * 4);
      sAT[f4 * 4 + 0][row] = (v.x - m) * r * g.x + bt.x;
      sAT[f4 * 4 + 1][row] = (v.y - m) * r * g.y + bt.y;
      sAT[f4 * 4 + 2][row] = (v.z - m) * r * g.z + bt.z;
      sAT[f4 * 4 + 3][row] = (v.w - m) * r * g.w + bt.w;
    }
#pragma unroll
    for (int q = 0; q < 4; ++q) {      // stage W_out tile 64x64
      int s = tid + q * 256;
      int kr = s >> 4, f4 = s & 15;
      float4 v = *reinterpret_cast<const float4*>(Wo + (size_t)(k0 + kr) * DM + n0 + f4 * 4);
      sB[kr][f4 * 4 + 0] = v.x; sB[kr][f4 * 4 + 1] = v.y;
      sB[kr][f4 * 4 + 2] = v.z; sB[kr][f4 * 4 + 3] = v.w;
    }
    __syncthreads();
#pragma unroll
    for (int kk = 0; kk < 64; ++kk) {
      float a[4], bb[4];
#pragma unroll
      for (int i = 0; i < 4; ++i) a[i] = sAT[kk][tr * 4 + i];
#pragma unroll
      for (int j = 0; j < 4; ++j) bb[j] = sB[kk][tc * 4 + j];
#pragma unroll
      for (int i = 0; i < 4; ++i)
#pragma unroll
        for (int j = 0; j < 4; ++j) acc[i][j] += a[i] * bb[j];
    }
  }
#pragma unroll
  for (int i = 0; i < 4; ++i) {
    int row = m0 + tr * 4 + i;
#pragma unroll
    for (int j = 0; j < 4; ++j) {
      int col = n0 + tc * 4 + j;
      out[(size_t)row * DM + col] = acc[i][j];
    }
  }
}

extern "C" void kernel_launch(void* const* d_in, const int* in_sizes, int n_in,
                              void* d_out, int out_size, void* d_ws, size_t ws_size,
                              hipStream_t stream) {
  const float* x       = (const float*)d_in[0];
  const float* W_in    = (const float*)d_in[1];
  const float* dt_bias = (const float*)d_in[2];
  const float* A_log   = (const float*)d_in[3];
  const float* D_param = (const float*)d_in[4];
  const float* gamma   = (const float*)d_in[5];
  const float* beta    = (const float*)d_in[6];
  const float* W_out   = (const float*)d_in[7];
  float* out = (float*)d_out;

  float* ws    = (float*)d_ws;
  float* xbcdt = ws;                                    // M_N * 648
  float* KV    = ws + (size_t)M_N * NPROJ;              // 32*8*64*64
  float* mu    = KV + (size_t)B_N * NH * DS * HD;       // M_N
  float* rstd  = mu + M_N;                              // M_N

  hipMemsetAsync(KV, 0, (size_t)B_N * NH * DS * HD * sizeof(float), stream);

  k_inproj <<<dim3((NPROJ + 63) / 64, M_N / 64), 256, 0, stream>>>(x, W_in, dt_bias, A_log, xbcdt);
  k_kv     <<<dim3(8, B_N * NH),                 256, 0, stream>>>(xbcdt, KV);
  k_ygemm  <<<dim3(DIN / 64, M_N / 64),          256, 0, stream>>>(xbcdt, KV, D_param);
  k_stats  <<<M_N / 4,                           256, 0, stream>>>(xbcdt, mu, rstd);
  k_outgemm<<<dim3(DM / 64, M_N / 64),           256, 0, stream>>>(xbcdt, mu, rstd, gamma, beta, W_out, out);
}

// Round 3
// 885.753 us; speedup vs baseline: 2.2572x; 2.2572x over previous
//
#include <hip/hip_runtime.h>
#include <hip/hip_bf16.h>
#include <math.h>

constexpr int B_N   = 32;
constexpr int L_N   = 4096;
constexpr int DM    = 256;
constexpr int DIN   = 512;
constexpr int DS    = 64;
constexpr int NH    = 8;
constexpr int HD    = 64;
constexpr int M_N   = B_N * L_N;     // 131072
constexpr int XBW   = 640;           // bf16 xbcdt row width: 512 V + 64 B + 64 C

typedef unsigned short u16;
typedef short s16x8 __attribute__((ext_vector_type(8)));
typedef float f32x4 __attribute__((ext_vector_type(4)));
typedef unsigned short u16x8 __attribute__((ext_vector_type(8)));
typedef unsigned short u16x4 __attribute__((ext_vector_type(4)));

__device__ __forceinline__ float softplusf(float z) {
  return (z > 20.f) ? z : log1pf(expf(z));
}
__device__ __forceinline__ u16 f2bf(float f) {
  unsigned u = __float_as_uint(f);
  u += 0x7FFFu + ((u >> 16) & 1u);
  return (u16)(u >> 16);
}
__device__ __forceinline__ float bf2f(u16 u) {
  return __uint_as_float(((unsigned)u) << 16);
}

#define GLDS(gsrc, ldst)                                                       \
  __builtin_amdgcn_global_load_lds(                                            \
      (const __attribute__((address_space(1))) void*)(gsrc),                   \
      (__attribute__((address_space(3))) void*)(ldst), 16, 0, 0)

// ---------- Kernel 0: fp32 -> bf16 conversions + weight transposes ----------
constexpr long CV0 = (long)M_N * DM / 4;       // x in float4 groups (8388608)
constexpr long CV1 = CV0 + 768L * 256;         // WinT elements (padded 648->768)
constexpr long CV2 = CV1 + 256L * 512;         // WoT elements
__global__ __launch_bounds__(256) void k_cvt(
    const float* __restrict__ x, const float* __restrict__ Wi,
    const float* __restrict__ Wo, u16* __restrict__ xb,
    u16* __restrict__ WinT, u16* __restrict__ WoT) {
  for (long i = (long)blockIdx.x * 256 + threadIdx.x; i < CV2;
       i += (long)gridDim.x * 256) {
    if (i < CV0) {
      float4 v = reinterpret_cast<const float4*>(x)[i];
      u16x4 o = {f2bf(v.x), f2bf(v.y), f2bf(v.z), f2bf(v.w)};
      reinterpret_cast<u16x4*>(xb)[i] = o;
    } else if (i < CV1) {
      long t = i - CV0; int n = (int)(t >> 8); int k = (int)(t & 255);
      WinT[t] = (n < 648) ? f2bf(Wi[(size_t)k * 648 + n]) : (u16)0;
    } else {
      long t = i - CV1; int n = (int)(t >> 9); int k = (int)(t & 511);
      WoT[t] = f2bf(Wo[(size_t)k * 256 + n]);
    }
  }
}

// ---------- Kernel 1: bf16 MFMA in-proj: [M,256]@[256,768] ----------
// n-tiles 0..4 -> bf16 xbcdt (V|B|C, stride 640); n-tile 5 -> dA fp32
__global__ __launch_bounds__(256) void k_inproj(
    const u16* __restrict__ xb, const u16* __restrict__ WinT,
    const float* __restrict__ dt_bias, const float* __restrict__ A_log,
    u16* __restrict__ xbcdt, float* __restrict__ dAv) {
  __shared__ __align__(16) short sA[128 * 32];
  __shared__ __align__(16) short sB[128 * 32];
  const int tid = threadIdx.x;
  const int wave = tid >> 6, lane = tid & 63;
  const int m0 = blockIdx.y * 128, n0 = blockIdx.x * 128;
  const int wr = wave >> 1, wc = wave & 1;
  f32x4 acc[4][4] = {};

  const u16* gA[2]; const u16* gB[2]; int ldsOff[2];
#pragma unroll
  for (int q = 0; q < 2; ++q) {
    int G = wave * 128 + q * 64 + lane;
    int row = G >> 2, kc = G & 3;
    gA[q] = xb + (size_t)(m0 + row) * DM + kc * 8;
    gB[q] = WinT + (size_t)(n0 + row) * DM + kc * 8;
    ldsOff[q] = (wave * 128 + q * 64) * 8;       // shorts, lane-uniform
  }

  for (int k0 = 0; k0 < DM; k0 += 32) {
    if (k0) __syncthreads();
#pragma unroll
    for (int q = 0; q < 2; ++q) GLDS(gA[q] + k0, sA + ldsOff[q]);
#pragma unroll
    for (int q = 0; q < 2; ++q) GLDS(gB[q] + k0, sB + ldsOff[q]);
    __syncthreads();
    const int kb = (lane >> 4) * 8;
    s16x8 af[4], bf[4];
#pragma unroll
    for (int i = 0; i < 4; ++i)
      af[i] = *(const s16x8*)&sA[(wr * 64 + i * 16 + (lane & 15)) * 32 + kb];
#pragma unroll
    for (int j = 0; j < 4; ++j)
      bf[j] = *(const s16x8*)&sB[(wc * 64 + j * 16 + (lane & 15)) * 32 + kb];
#pragma unroll
    for (int i = 0; i < 4; ++i)
#pragma unroll
      for (int j = 0; j < 4; ++j)
        acc[i][j] = __builtin_amdgcn_mfma_f32_16x16x32_bf16(af[i], bf[j], acc[i][j], 0, 0, 0);
  }

  const int cl = lane & 15;
  const int row_base = m0 + wr * 64 + ((lane >> 4) << 2);
  if (n0 < 640) {
    const int col_base = n0 + wc * 64;
#pragma unroll
    for (int i = 0; i < 4; ++i)
#pragma unroll
      for (int r = 0; r < 4; ++r) {
        int row = row_base + i * 16 + r;
#pragma unroll
        for (int j = 0; j < 4; ++j)
          xbcdt[(size_t)row * XBW + col_base + j * 16 + cl] = f2bf(acc[i][j][r]);
      }
  } else if (wc == 0 && cl < 8) {
    const float nAe = -expf(A_log[cl]);
    const float db = dt_bias[cl];
#pragma unroll
    for (int i = 0; i < 4; ++i)
#pragma unroll
      for (int r = 0; r < 4; ++r) {
        int row = row_base + i * 16 + r;
        dAv[(size_t)row * NH + cl] = softplusf(acc[i][0][r] + db) * nAe;
      }
  }
}

// ---------- Kernel 2: KV[b,h,s,p] = sum_l B[l,s] * V[l,h,p] * dA[l,h] ----------
__global__ __launch_bounds__(256) void k_kv(
    const u16* __restrict__ xb, const float* __restrict__ dAv,
    float* __restrict__ KV) {
  const int bh = blockIdx.y;
  const int b = bh >> 3, h = bh & 7;
  const int l0 = blockIdx.x * (L_N / 8);
  const int tid = threadIdx.x;
  __shared__ float sB[8][64];
  __shared__ float sV[8][64];
  __shared__ float sdA[8];
  const int s_idx = tid >> 2;
  const int p0 = (tid & 3) * 16;
  float acc[16] = {};
  for (int lt = 0; lt < L_N / 8; lt += 8) {
    __syncthreads();
    if (tid < 64) {
      int row = tid >> 3, c8 = (tid & 7) * 8;
      u16x8 v = *(const u16x8*)&xb[(size_t)(b * L_N + l0 + lt + row) * XBW + DIN + c8];
#pragma unroll
      for (int jj = 0; jj < 8; ++jj) sB[row][c8 + jj] = bf2f(v[jj]);
    } else if (tid < 128) {
      int t = tid - 64;
      int row = t >> 3, c8 = (t & 7) * 8;
      u16x8 v = *(const u16x8*)&xb[(size_t)(b * L_N + l0 + lt + row) * XBW + h * HD + c8];
#pragma unroll
      for (int jj = 0; jj < 8; ++jj) sV[row][c8 + jj] = bf2f(v[jj]);
    } else if (tid < 136) {
      int row = tid - 128;
      sdA[row] = dAv[(size_t)(b * L_N + l0 + lt + row) * NH + h];
    }
    __syncthreads();
#pragma unroll
    for (int i = 0; i < 8; ++i) {
      float w = sB[i][s_idx] * sdA[i];
#pragma unroll
      for (int j = 0; j < 16; ++j) acc[j] += w * sV[i][p0 + j];
    }
  }
  float* dst = KV + ((size_t)bh * 64 + s_idx) * 64 + p0;
#pragma unroll
  for (int j = 0; j < 16; ++j) atomicAdd(dst + j, acc[j]);
}

// ---------- Kernel 3: y = C @ KV + V*D, bf16 in-place over V ----------
__global__ __launch_bounds__(256) void k_ygemm(
    u16* __restrict__ xb, const float* __restrict__ KV,
    const float* __restrict__ Dp) {
  __shared__ float sCT[64][65];
  __shared__ float sW[64][64];
  const int n0 = blockIdx.x * 64;
  const int m0 = blockIdx.y * 64;
  const int b = m0 >> 12;
  const int h = n0 >> 6;
  const int tid = threadIdx.x;
  const int tr = tid >> 4, tc = tid & 15;
#pragma unroll
  for (int q = 0; q < 2; ++q) {          // stage C^T (64 rows x 64 s)
    int s = tid + q * 256;
    int row = s >> 3, c8 = (s & 7) * 8;
    u16x8 v = *(const u16x8*)&xb[(size_t)(m0 + row) * XBW + DIN + DS + c8];
#pragma unroll
    for (int jj = 0; jj < 8; ++jj) sCT[c8 + jj][row] = bf2f(v[jj]);
  }
  {
    const float* kvb = KV + (size_t)(b * NH + h) * 64 * 64;
#pragma unroll
    for (int q = 0; q < 4; ++q) {
      int s = tid + q * 256;
      int sr = s >> 4, f4 = s & 15;
      float4 v = *reinterpret_cast<const float4*>(kvb + sr * 64 + f4 * 4);
      sW[sr][f4 * 4 + 0] = v.x; sW[sr][f4 * 4 + 1] = v.y;
      sW[sr][f4 * 4 + 2] = v.z; sW[sr][f4 * 4 + 3] = v.w;
    }
  }
  __syncthreads();
  float acc[4][4] = {};
#pragma unroll
  for (int kk = 0; kk < 64; ++kk) {
    float a[4], bb[4];
#pragma unroll
    for (int i = 0; i < 4; ++i) a[i] = sCT[kk][tr * 4 + i];
#pragma unroll
    for (int j = 0; j < 4; ++j) bb[j] = sW[kk][tc * 4 + j];
#pragma unroll
    for (int i = 0; i < 4; ++i)
#pragma unroll
      for (int j = 0; j < 4; ++j) acc[i][j] += a[i] * bb[j];
  }
  const float dscale = Dp[h];
#pragma unroll
  for (int i = 0; i < 4; ++i) {
    int row = m0 + tr * 4 + i;
#pragma unroll
    for (int j = 0; j < 4; ++j) {
      int col = n0 + tc * 4 + j;
      size_t idx = (size_t)row * XBW + col;
      float v = bf2f(xb[idx]);
      xb[idx] = f2bf(acc[i][j] + v * dscale);
    }
  }
}

// ---------- Kernel 4: fused row-stats + LayerNorm, in place (bf16) ----------
__global__ __launch_bounds__(256) void k_statsln(
    u16* __restrict__ xb, const float* __restrict__ g, const float* __restrict__ bt) {
  const int w = threadIdx.x >> 6, lane = threadIdx.x & 63;
  const size_t row = (size_t)blockIdx.x * 4 + w;
  u16* yr = xb + row * XBW;
  u16x8 v = *(const u16x8*)(yr + lane * 8);
  float f[8];
  float s = 0.f, q = 0.f;
#pragma unroll
  for (int j = 0; j < 8; ++j) {
    f[j] = bf2f(v[j]);
    s += f[j]; q += f[j] * f[j];
  }
#pragma unroll
  for (int off = 1; off < 64; off <<= 1) {
    s += __shfl_xor(s, off);
    q += __shfl_xor(q, off);
  }
  const float mu = s / DIN;
  const float rstd = rsqrtf(q / DIN - mu * mu + 1e-5f);
  float4 g0 = *reinterpret_cast<const float4*>(g + lane * 8);
  float4 g1 = *reinterpret_cast<const float4*>(g + lane * 8 + 4);
  float4 b0 = *reinterpret_cast<const float4*>(bt + lane * 8);
  float4 b1 = *reinterpret_cast<const float4*>(bt + lane * 8 + 4);
  float gg[8] = {g0.x, g0.y, g0.z, g0.w, g1.x, g1.y, g1.z, g1.w};
  float bb[8] = {b0.x, b0.y, b0.z, b0.w, b1.x, b1.y, b1.z, b1.w};
  u16x8 o;
#pragma unroll
  for (int j = 0; j < 8; ++j)
    o[j] = f2bf((f[j] - mu) * rstd * gg[j] + bb[j]);
  *(u16x8*)(yr + lane * 8) = o;
}

// ---------- Kernel 5: bf16 MFMA out-proj: [M,512]@[512,256] ----------
__global__ __launch_bounds__(256) void k_outgemm(
    const u16* __restrict__ xbcdt, const u16* __restrict__ WoT,
    float* __restrict__ out) {
  __shared__ __align__(16) short sA[128 * 32];
  __shared__ __align__(16) short sB[128 * 32];
  const int tid = threadIdx.x;
  const int wave = tid >> 6, lane = tid & 63;
  const int m0 = blockIdx.y * 128, n0 = blockIdx.x * 128;
  const int wr = wave >> 1, wc = wave & 1;
  f32x4 acc[4][4] = {};

  const u16* gA[2]; const u16* gB[2]; int ldsOff[2];
#pragma unroll
  for (int q = 0; q < 2; ++q) {
    int G = wave * 128 + q * 64 + lane;
    int row = G >> 2, kc = G & 3;
    gA[q] = xbcdt + (size_t)(m0 + row) * XBW + kc * 8;   // LN(y) in cols 0..511
    gB[q] = WoT + (size_t)(n0 + row) * DIN + kc * 8;
    ldsOff[q] = (wave * 128 + q * 64) * 8;
  }

  for (int k0 = 0; k0 < DIN; k0 += 32) {
    if (k0) __syncthreads();
#pragma unroll
    for (int q = 0; q < 2; ++q) GLDS(gA[q] + k0, sA + ldsOff[q]);
#pragma unroll
    for (int q = 0; q < 2; ++q) GLDS(gB[q] + k0, sB + ldsOff[q]);
    __syncthreads();
    const int kb = (lane >> 4) * 8;
    s16x8 af[4], bf[4];
#pragma unroll
    for (int i = 0; i < 4; ++i)
      af[i] = *(const s16x8*)&sA[(wr * 64 + i * 16 + (lane & 15)) * 32 + kb];
#pragma unroll
    for (int j = 0; j < 4; ++j)
      bf[j] = *(const s16x8*)&sB[(wc * 64 + j * 16 + (lane & 15)) * 32 + kb];
#pragma unroll
    for (int i = 0; i < 4; ++i)
#pragma unroll
      for (int j = 0; j < 4; ++j)
        acc[i][j] = __builtin_amdgcn_mfma_f32_16x16x32_bf16(af[i], bf[j], acc[i][j], 0, 0, 0);
  }

  const int cl = lane & 15;
  const int row_base = m0 + wr * 64 + ((lane >> 4) << 2);
  const int col_base = n0 + wc * 64;
#pragma unroll
  for (int i = 0; i < 4; ++i)
#pragma unroll
    for (int r = 0; r < 4; ++r) {
      int row = row_base + i * 16 + r;
#pragma unroll
      for (int j = 0; j < 4; ++j)
        out[(size_t)row * DM + col_base + j * 16 + cl] = acc[i][j][r];
    }
}

extern "C" void kernel_launch(void* const* d_in, const int* in_sizes, int n_in,
                              void* d_out, int out_size, void* d_ws, size_t ws_size,
                              hipStream_t stream) {
  const float* x       = (const float*)d_in[0];
  const float* W_in    = (const float*)d_in[1];
  const float* dt_bias = (const float*)d_in[2];
  const float* A_log   = (const float*)d_in[3];
  const float* D_param = (const float*)d_in[4];
  const float* gamma   = (const float*)d_in[5];
  const float* beta    = (const float*)d_in[6];
  const float* W_out   = (const float*)d_in[7];
  float* out = (float*)d_out;

  u16* ws    = (u16*)d_ws;
  u16* xb    = ws;                                   // M*256 bf16
  u16* WinT  = xb + (size_t)M_N * DM;                // 768*256
  u16* WoT   = WinT + 768L * 256;                    // 256*512
  u16* xbcdt = WoT + 256L * 512;                     // M*640 bf16
  float* dAv = (float*)(xbcdt + (size_t)M_N * XBW);  // M*8 fp32
  float* KV  = dAv + (size_t)M_N * NH;               // 32*8*64*64 fp32

  hipMemsetAsync(KV, 0, (size_t)B_N * NH * DS * HD * sizeof(float), stream);

  k_cvt    <<<4096, 256, 0, stream>>>(x, W_in, W_out, xb, WinT, WoT);
  k_inproj <<<dim3(6, M_N / 128), 256, 0, stream>>>(xb, WinT, dt_bias, A_log, xbcdt, dAv);
  k_kv     <<<dim3(8, B_N * NH),  256, 0, stream>>>(xbcdt, dAv, KV);
  k_ygemm  <<<dim3(DIN / 64, M_N / 64), 256, 0, stream>>>(xbcdt, KV, D_param);
  k_statsln<<<M_N / 4, 256, 0, stream>>>(xbcdt, gamma, beta);
  k_outgemm<<<dim3(DM / 128, M_N / 128), 256, 0, stream>>>(xbcdt, WoT, out);
}

// Round 5
// 434.085 us; speedup vs baseline: 4.6058x; 2.0405x over previous
//
#include <hip/hip_runtime.h>
#include <hip/hip_bf16.h>
#include <math.h>

constexpr int B_N   = 32;
constexpr int L_N   = 4096;
constexpr int DM    = 256;
constexpr int DIN   = 512;
constexpr int DS    = 64;
constexpr int NH    = 8;
constexpr int HD    = 64;
constexpr int M_N   = B_N * L_N;     // 131072
constexpr int XBW   = 640;           // bf16 xbcdt row: 512 V + 64 B + 64 C

typedef unsigned short u16;
typedef short s16x4 __attribute__((ext_vector_type(4)));
typedef short s16x8 __attribute__((ext_vector_type(8)));
typedef float f32x4 __attribute__((ext_vector_type(4)));
typedef unsigned short u16x8 __attribute__((ext_vector_type(8)));
typedef unsigned short u16x4 __attribute__((ext_vector_type(4)));

__device__ __forceinline__ float softplusf(float z) {
  return (z > 20.f) ? z : log1pf(expf(z));
}
__device__ __forceinline__ u16 f2bf(float f) {
  unsigned u = __float_as_uint(f);
  u += 0x7FFFu + ((u >> 16) & 1u);
  return (u16)(u >> 16);
}
__device__ __forceinline__ float bf2f(u16 u) {
  return __uint_as_float(((unsigned)u) << 16);
}
__device__ __forceinline__ s16x8 ld_frag2(const short* p) {
  s16x4 lo = *(const s16x4*)p;
  s16x4 hi = *(const s16x4*)(p + 4);
  s16x8 r;
  r[0]=lo[0]; r[1]=lo[1]; r[2]=lo[2]; r[3]=lo[3];
  r[4]=hi[0]; r[5]=hi[1]; r[6]=hi[2]; r[7]=hi[3];
  return r;
}

#define GLDS(gsrc, ldst)                                                       \
  __builtin_amdgcn_global_load_lds(                                            \
      (const __attribute__((address_space(1))) void*)(gsrc),                   \
      (__attribute__((address_space(3))) void*)(ldst), 16, 0, 0)

// ---------- Kernel 0: fp32 -> bf16 conversions + weight transposes ----------
constexpr long CV0 = (long)M_N * DM / 4;       // x in float4 groups
constexpr long CV1 = CV0 + 768L * 256;         // WinT elements (padded 648->768)
constexpr long CV2 = CV1 + 256L * 512;         // WoT elements
__global__ __launch_bounds__(256) void k_cvt(
    const float* __restrict__ x, const float* __restrict__ Wi,
    const float* __restrict__ Wo, u16* __restrict__ xb,
    u16* __restrict__ WinT, u16* __restrict__ WoT) {
  for (long i = (long)blockIdx.x * 256 + threadIdx.x; i < CV2;
       i += (long)gridDim.x * 256) {
    if (i < CV0) {
      float4 v = reinterpret_cast<const float4*>(x)[i];
      u16x4 o = {f2bf(v.x), f2bf(v.y), f2bf(v.z), f2bf(v.w)};
      reinterpret_cast<u16x4*>(xb)[i] = o;
    } else if (i < CV1) {
      long t = i - CV0; int n = (int)(t >> 8); int k = (int)(t & 255);
      WinT[t] = (n < 648) ? f2bf(Wi[(size_t)k * 648 + n]) : (u16)0;
    } else {
      long t = i - CV1; int n = (int)(t >> 9); int k = (int)(t & 511);
      WoT[t] = f2bf(Wo[(size_t)k * 256 + n]);
    }
  }
}

// ---------- Kernel 1: bf16 MFMA in-proj: [M,256]@[256,768] ----------
// n-tiles 0..4 -> bf16 xbcdt (V|B|C, stride 640); n-tile 5 -> dA fp32 [M][8]
__global__ __launch_bounds__(256) void k_inproj(
    const u16* __restrict__ xb, const u16* __restrict__ WinT,
    const float* __restrict__ dt_bias, const float* __restrict__ A_log,
    u16* __restrict__ xbcdt, float* __restrict__ dAv) {
  __shared__ __align__(16) short sA[128 * 32];
  __shared__ __align__(16) short sB[128 * 32];
  const int tid = threadIdx.x;
  const int wave = tid >> 6, lane = tid & 63;
  const int m0 = blockIdx.y * 128, n0 = blockIdx.x * 128;
  const int wr = wave >> 1, wc = wave & 1;
  f32x4 acc[4][4] = {};

  const u16* gA[2]; const u16* gB[2]; int ldsOff[2];
#pragma unroll
  for (int q = 0; q < 2; ++q) {
    int G = wave * 128 + q * 64 + lane;
    int row = G >> 2, kc = G & 3;
    gA[q] = xb + (size_t)(m0 + row) * DM + kc * 8;
    gB[q] = WinT + (size_t)(n0 + row) * DM + kc * 8;
    ldsOff[q] = (wave * 128 + q * 64) * 8;
  }

  for (int k0 = 0; k0 < DM; k0 += 32) {
    if (k0) __syncthreads();
#pragma unroll
    for (int q = 0; q < 2; ++q) GLDS(gA[q] + k0, sA + ldsOff[q]);
#pragma unroll
    for (int q = 0; q < 2; ++q) GLDS(gB[q] + k0, sB + ldsOff[q]);
    __syncthreads();
    const int kb = (lane >> 4) * 8;
    s16x8 af[4], bf[4];
#pragma unroll
    for (int i = 0; i < 4; ++i)
      af[i] = *(const s16x8*)&sA[(wr * 64 + i * 16 + (lane & 15)) * 32 + kb];
#pragma unroll
    for (int j = 0; j < 4; ++j)
      bf[j] = *(const s16x8*)&sB[(wc * 64 + j * 16 + (lane & 15)) * 32 + kb];
#pragma unroll
    for (int i = 0; i < 4; ++i)
#pragma unroll
      for (int j = 0; j < 4; ++j)
        acc[i][j] = __builtin_amdgcn_mfma_f32_16x16x32_bf16(af[i], bf[j], acc[i][j], 0, 0, 0);
  }

  const int cl = lane & 15;
  const int row_base = m0 + wr * 64 + ((lane >> 4) << 2);
  if (n0 < 640) {
    const int col_base = n0 + wc * 64;
#pragma unroll
    for (int i = 0; i < 4; ++i)
#pragma unroll
      for (int r = 0; r < 4; ++r) {
        int row = row_base + i * 16 + r;
#pragma unroll
        for (int j = 0; j < 4; ++j)
          xbcdt[(size_t)row * XBW + col_base + j * 16 + cl] = f2bf(acc[i][j][r]);
      }
  } else if (wc == 0 && cl < 8) {
    const float nAe = -expf(A_log[cl]);
    const float db = dt_bias[cl];
#pragma unroll
    for (int i = 0; i < 4; ++i)
#pragma unroll
      for (int r = 0; r < 4; ++r) {
        int row = row_base + i * 16 + r;
        dAv[(size_t)row * NH + cl] = softplusf(acc[i][0][r] + db) * nAe;
      }
  }
}

// ---------- Kernel 1b: Bt[b][s][l] = B_ssm (xbcdt cols 512..575) transposed --
__global__ __launch_bounds__(256) void k_bt(
    const u16* __restrict__ xbcdt, u16* __restrict__ Bt) {
  __shared__ u16 sT[64][72];           // [l][s], pad 72
  const int m0 = blockIdx.x * 64;
  const int b  = m0 >> 12;
  const int l0 = m0 & (L_N - 1);
  const int tid = threadIdx.x;
#pragma unroll
  for (int q = 0; q < 2; ++q) {
    int r = (tid >> 3) + q * 32, c8 = (tid & 7) * 8;
    u16x8 v = *(const u16x8*)&xbcdt[(size_t)(m0 + r) * XBW + DIN + c8];
#pragma unroll
    for (int jj = 0; jj < 8; ++jj) sT[r][c8 + jj] = v[jj];
  }
  __syncthreads();
#pragma unroll
  for (int q = 0; q < 2; ++q) {
    int s = (tid >> 3) + q * 32, lc8 = (tid & 7) * 8;
    u16x8 o;
#pragma unroll
    for (int jj = 0; jj < 8; ++jj) o[jj] = sT[lc8 + jj][s];
    *(u16x8*)&Bt[((size_t)(b * 64 + s)) * L_N + l0 + lc8] = o;
  }
}

// ---------- Kernel 2: MFMA KV-partials: KVp[chunk][bh][s][p] ----------
__global__ __launch_bounds__(256) void k_kv(
    const u16* __restrict__ xbcdt, const u16* __restrict__ Bt,
    const float* __restrict__ dAv, float* __restrict__ KVp) {
  const int bh = blockIdx.y;
  const int b = bh >> 3, h = bh & 7;
  const int l0 = blockIdx.x * (L_N / 4);   // 1024-l chunk
  const int tid = threadIdx.x;
  const int wave = tid >> 6, lane = tid & 63;
  const int wr = wave >> 1, wc = wave & 1;
  const int fr = lane & 15, fq = lane >> 4;
  __shared__ short sBt[64 * 36];   // [s][l-chunk32] pad 36
  __shared__ short sVt[64 * 36];   // [p][l-chunk32] (scaled by dA)
  f32x4 acc[2][2] = {};
  const int ts = tid >> 2, tlc = tid & 3;      // B staging
  const int tl = tid >> 3, tpg = tid & 7;      // V staging

  for (int ks = 0; ks < L_N / 4; ks += 32) {
    u16x8 vb = *(const u16x8*)&Bt[((size_t)(b * 64 + ts)) * L_N + l0 + ks + tlc * 8];
    const int gl = b * L_N + l0 + ks + tl;
    u16x8 vv = *(const u16x8*)&xbcdt[(size_t)gl * XBW + h * HD + tpg * 8];
    const float da = dAv[(size_t)gl * NH + h];
    __syncthreads();
    *(s16x4*)&sBt[ts * 36 + tlc * 8]     = *(s16x4*)&vb;
    *(s16x4*)&sBt[ts * 36 + tlc * 8 + 4] = *((s16x4*)&vb + 1);
#pragma unroll
    for (int jj = 0; jj < 8; ++jj)
      sVt[(tpg * 8 + jj) * 36 + tl] = (short)f2bf(bf2f(vv[jj]) * da);
    __syncthreads();
    s16x8 af[2], bf[2];
#pragma unroll
    for (int i = 0; i < 2; ++i)
      af[i] = ld_frag2(&sBt[(wr * 32 + i * 16 + fr) * 36 + fq * 8]);
#pragma unroll
    for (int j = 0; j < 2; ++j)
      bf[j] = ld_frag2(&sVt[(wc * 32 + j * 16 + fr) * 36 + fq * 8]);
#pragma unroll
    for (int i = 0; i < 2; ++i)
#pragma unroll
      for (int j = 0; j < 2; ++j)
        acc[i][j] = __builtin_amdgcn_mfma_f32_16x16x32_bf16(af[i], bf[j], acc[i][j], 0, 0, 0);
  }
  float* dst = KVp + ((size_t)(blockIdx.x * 256 + bh)) * 4096;
#pragma unroll
  for (int i = 0; i < 2; ++i)
#pragma unroll
    for (int j = 0; j < 2; ++j)
#pragma unroll
      for (int r = 0; r < 4; ++r) {
        int s = wr * 32 + i * 16 + fq * 4 + r;
        int p = wc * 32 + j * 16 + fr;
        dst[s * 64 + p] = acc[i][j][r];
      }
}

// ---------- Kernel 3: y = C @ KV + V*D, bf16 in-place over V ----------
__global__ __launch_bounds__(256) void k_ygemm(
    u16* __restrict__ xb, const float* __restrict__ KVp,
    const float* __restrict__ Dp) {
  __shared__ float sCT[64][65];
  __shared__ float sW[64][64];
  const int n0 = blockIdx.x * 64;
  const int m0 = blockIdx.y * 64;
  const int b = m0 >> 12;
  const int h = n0 >> 6;
  const int tid = threadIdx.x;
  const int tr = tid >> 4, tc = tid & 15;
#pragma unroll
  for (int q = 0; q < 2; ++q) {          // stage C^T (64 rows x 64 s)
    int s = tid + q * 256;
    int row = s >> 3, c8 = (s & 7) * 8;
    u16x8 v = *(const u16x8*)&xb[(size_t)(m0 + row) * XBW + DIN + DS + c8];
#pragma unroll
    for (int jj = 0; jj < 8; ++jj) sCT[c8 + jj][row] = bf2f(v[jj]);
  }
  {
    const float* kvb = KVp + (size_t)(b * NH + h) * 4096;
#pragma unroll
    for (int q = 0; q < 4; ++q) {        // stage KV = sum of 4 partials
      int s = tid + q * 256;
      int sr = s >> 4, f4 = s & 15;
      float4 v0 = *reinterpret_cast<const float4*>(kvb + sr * 64 + f4 * 4);
      float4 v1 = *reinterpret_cast<const float4*>(kvb + 1048576 + sr * 64 + f4 * 4);
      float4 v2 = *reinterpret_cast<const float4*>(kvb + 2097152 + sr * 64 + f4 * 4);
      float4 v3 = *reinterpret_cast<const float4*>(kvb + 3145728 + sr * 64 + f4 * 4);
      sW[sr][f4 * 4 + 0] = v0.x + v1.x + v2.x + v3.x;
      sW[sr][f4 * 4 + 1] = v0.y + v1.y + v2.y + v3.y;
      sW[sr][f4 * 4 + 2] = v0.z + v1.z + v2.z + v3.z;
      sW[sr][f4 * 4 + 3] = v0.w + v1.w + v2.w + v3.w;
    }
  }
  __syncthreads();
  float acc[4][4] = {};
#pragma unroll
  for (int kk = 0; kk < 64; ++kk) {
    float a[4], bb[4];
#pragma unroll
    for (int i = 0; i < 4; ++i) a[i] = sCT[kk][tr * 4 + i];
#pragma unroll
    for (int j = 0; j < 4; ++j) bb[j] = sW[kk][tc * 4 + j];
#pragma unroll
    for (int i = 0; i < 4; ++i)
#pragma unroll
      for (int j = 0; j < 4; ++j) acc[i][j] += a[i] * bb[j];
  }
  const float dscale = Dp[h];
#pragma unroll
  for (int i = 0; i < 4; ++i) {
    int row = m0 + tr * 4 + i;
#pragma unroll
    for (int j = 0; j < 4; ++j) {
      int col = n0 + tc * 4 + j;
      size_t idx = (size_t)row * XBW + col;
      float v = bf2f(xb[idx]);
      xb[idx] = f2bf(acc[i][j] + v * dscale);
    }
  }
}

// ---------- Kernel 4: fused row-stats + LayerNorm, in place (bf16) ----------
__global__ __launch_bounds__(256) void k_statsln(
    u16* __restrict__ xb, const float* __restrict__ g, const float* __restrict__ bt) {
  const int w = threadIdx.x >> 6, lane = threadIdx.x & 63;
  const size_t row = (size_t)blockIdx.x * 4 + w;
  u16* yr = xb + row * XBW;
  u16x8 v = *(const u16x8*)(yr + lane * 8);
  float f[8];
  float s = 0.f, q = 0.f;
#pragma unroll
  for (int j = 0; j < 8; ++j) {
    f[j] = bf2f(v[j]);
    s += f[j]; q += f[j] * f[j];
  }
#pragma unroll
  for (int off = 1; off < 64; off <<= 1) {
    s += __shfl_xor(s, off);
    q += __shfl_xor(q, off);
  }
  const float mu = s / DIN;
  const float rstd = rsqrtf(q / DIN - mu * mu + 1e-5f);
  float4 g0 = *reinterpret_cast<const float4*>(g + lane * 8);
  float4 g1 = *reinterpret_cast<const float4*>(g + lane * 8 + 4);
  float4 b0 = *reinterpret_cast<const float4*>(bt + lane * 8);
  float4 b1 = *reinterpret_cast<const float4*>(bt + lane * 8 + 4);
  float gg[8] = {g0.x, g0.y, g0.z, g0.w, g1.x, g1.y, g1.z, g1.w};
  float bb[8] = {b0.x, b0.y, b0.z, b0.w, b1.x, b1.y, b1.z, b1.w};
  u16x8 o;
#pragma unroll
  for (int j = 0; j < 8; ++j)
    o[j] = f2bf((f[j] - mu) * rstd * gg[j] + bb[j]);
  *(u16x8*)(yr + lane * 8) = o;
}

// ---------- Kernel 5: bf16 MFMA out-proj: [M,512]@[512,256] ----------
__global__ __launch_bounds__(256) void k_outgemm(
    const u16* __restrict__ xbcdt, const u16* __restrict__ WoT,
    float* __restrict__ out) {
  __shared__ __align__(16) short sA[128 * 32];
  __shared__ __align__(16) short sB[128 * 32];
  const int tid = threadIdx.x;
  const int wave = tid >> 6, lane = tid & 63;
  const int m0 = blockIdx.y * 128, n0 = blockIdx.x * 128;
  const int wr = wave >> 1, wc = wave & 1;
  f32x4 acc[4][4] = {};

  const u16* gA[2]; const u16* gB[2]; int ldsOff[2];
#pragma unroll
  for (int q = 0; q < 2; ++q) {
    int G = wave * 128 + q * 64 + lane;
    int row = G >> 2, kc = G & 3;
    gA[q] = xbcdt + (size_t)(m0 + row) * XBW + kc * 8;
    gB[q] = WoT + (size_t)(n0 + row) * DIN + kc * 8;
    ldsOff[q] = (wave * 128 + q * 64) * 8;
  }

  for (int k0 = 0; k0 < DIN; k0 += 32) {
    if (k0) __syncthreads();
#pragma unroll
    for (int q = 0; q < 2; ++q) GLDS(gA[q] + k0, sA + ldsOff[q]);
#pragma unroll
    for (int q = 0; q < 2; ++q) GLDS(gB[q] + k0, sB + ldsOff[q]);
    __syncthreads();
    const int kb = (lane >> 4) * 8;
    s16x8 af[4], bf[4];
#pragma unroll
    for (int i = 0; i < 4; ++i)
      af[i] = *(const s16x8*)&sA[(wr * 64 + i * 16 + (lane & 15)) * 32 + kb];
#pragma unroll
    for (int j = 0; j < 4; ++j)
      bf[j] = *(const s16x8*)&sB[(wc * 64 + j * 16 + (lane & 15)) * 32 + kb];
#pragma unroll
    for (int i = 0; i < 4; ++i)
#pragma unroll
      for (int j = 0; j < 4; ++j)
        acc[i][j] = __builtin_amdgcn_mfma_f32_16x16x32_bf16(af[i], bf[j], acc[i][j], 0, 0, 0);
  }

  const int cl = lane & 15;
  const int row_base = m0 + wr * 64 + ((lane >> 4) << 2);
  const int col_base = n0 + wc * 64;
#pragma unroll
  for (int i = 0; i < 4; ++i)
#pragma unroll
    for (int r = 0; r < 4; ++r) {
      int row = row_base + i * 16 + r;
#pragma unroll
      for (int j = 0; j < 4; ++j)
        out[(size_t)row * DM + col_base + j * 16 + cl] = acc[i][j][r];
    }
}

extern "C" void kernel_launch(void* const* d_in, const int* in_sizes, int n_in,
                              void* d_out, int out_size, void* d_ws, size_t ws_size,
                              hipStream_t stream) {
  const float* x       = (const float*)d_in[0];
  const float* W_in    = (const float*)d_in[1];
  const float* dt_bias = (const float*)d_in[2];
  const float* A_log   = (const float*)d_in[3];
  const float* D_param = (const float*)d_in[4];
  const float* gamma   = (const float*)d_in[5];
  const float* beta    = (const float*)d_in[6];
  const float* W_out   = (const float*)d_in[7];
  float* out = (float*)d_out;

  u16* ws    = (u16*)d_ws;
  u16* xb    = ws;                                    // M*256 bf16
  u16* WinT  = xb + (size_t)M_N * DM;                 // 768*256
  u16* WoT   = WinT + 768L * 256;                     // 256*512
  u16* xbcdt = WoT + 256L * 512;                      // M*640 bf16
  u16* Bt    = xbcdt + (size_t)M_N * XBW;             // 32*64*4096 bf16
  float* dAv = (float*)(Bt + (size_t)B_N * 64 * L_N); // M*8 fp32
  float* KVp = dAv + (size_t)M_N * NH;                // 4*256*4096 fp32

  k_cvt    <<<4096, 256, 0, stream>>>(x, W_in, W_out, xb, WinT, WoT);
  k_inproj <<<dim3(6, M_N / 128), 256, 0, stream>>>(xb, WinT, dt_bias, A_log, xbcdt, dAv);
  k_bt     <<<M_N / 64, 256, 0, stream>>>(xbcdt, Bt);
  k_kv     <<<dim3(4, B_N * NH), 256, 0, stream>>>(xbcdt, Bt, dAv, KVp);
  k_ygemm  <<<dim3(DIN / 64, M_N / 64), 256, 0, stream>>>(xbcdt, KVp, D_param);
  k_statsln<<<M_N / 4, 256, 0, stream>>>(xbcdt, gamma, beta);
  k_outgemm<<<dim3(DM / 128, M_N / 128), 256, 0, stream>>>(xbcdt, WoT, out);
}

// Round 7
// 397.884 us; speedup vs baseline: 5.0249x; 1.0910x over previous
//
#include <hip/hip_runtime.h>
#include <hip/hip_bf16.h>
#include <math.h>

constexpr int B_N   = 32;
constexpr int L_N   = 4096;
constexpr int DM    = 256;
constexpr int DIN   = 512;
constexpr int DS    = 64;
constexpr int NH    = 8;
constexpr int HD    = 64;
constexpr int M_N   = B_N * L_N;     // 131072
constexpr int XBW   = 640;           // bf16 xbcdt row: 512 V + 64 B + 64 C

typedef unsigned short u16;
typedef short s16x4 __attribute__((ext_vector_type(4)));
typedef short s16x8 __attribute__((ext_vector_type(8)));
typedef float f32x4 __attribute__((ext_vector_type(4)));
typedef unsigned short u16x8 __attribute__((ext_vector_type(8)));
typedef unsigned short u16x4 __attribute__((ext_vector_type(4)));

__device__ __forceinline__ float softplusf(float z) {
  return (z > 20.f) ? z : log1pf(expf(z));
}
__device__ __forceinline__ u16 f2bf(float f) {
  unsigned u = __float_as_uint(f);
  u += 0x7FFFu + ((u >> 16) & 1u);
  return (u16)(u >> 16);
}
__device__ __forceinline__ float bf2f(u16 u) {
  return __uint_as_float(((unsigned)u) << 16);
}
__device__ __forceinline__ s16x8 ld_frag2(const short* p) {
  s16x4 lo = *(const s16x4*)p;
  s16x4 hi = *(const s16x4*)(p + 4);
  s16x8 r;
  r[0]=lo[0]; r[1]=lo[1]; r[2]=lo[2]; r[3]=lo[3];
  r[4]=hi[0]; r[5]=hi[1]; r[6]=hi[2]; r[7]=hi[3];
  return r;
}

#define GLDS(gsrc, ldst)                                                       \
  __builtin_amdgcn_global_load_lds(                                            \
      (const __attribute__((address_space(1))) void*)(gsrc),                   \
      (__attribute__((address_space(3))) void*)(ldst), 16, 0, 0)

// ---------- Kernel 0: fp32 -> bf16 conversions + weight transposes ----------
constexpr long CV0 = (long)M_N * DM / 4;       // x in float4 groups
constexpr long CV1 = CV0 + 768L * 256;         // WinT elements (padded 648->768)
constexpr long CV2 = CV1 + 256L * 512;         // WoT elements
__global__ __launch_bounds__(256) void k_cvt(
    const float* __restrict__ x, const float* __restrict__ Wi,
    const float* __restrict__ Wo, u16* __restrict__ xb,
    u16* __restrict__ WinT, u16* __restrict__ WoT) {
  for (long i = (long)blockIdx.x * 256 + threadIdx.x; i < CV2;
       i += (long)gridDim.x * 256) {
    if (i < CV0) {
      float4 v = reinterpret_cast<const float4*>(x)[i];
      u16x4 o = {f2bf(v.x), f2bf(v.y), f2bf(v.z), f2bf(v.w)};
      reinterpret_cast<u16x4*>(xb)[i] = o;
    } else if (i < CV1) {
      long t = i - CV0; int n = (int)(t >> 8); int k = (int)(t & 255);
      WinT[t] = (n < 648) ? f2bf(Wi[(size_t)k * 648 + n]) : (u16)0;
    } else {
      long t = i - CV1; int n = (int)(t >> 9); int k = (int)(t & 511);
      WoT[t] = f2bf(Wo[(size_t)k * 256 + n]);
    }
  }
}

// ---------- Kernel 1: bf16 MFMA in-proj: [M,256]@[256,768] ----------
__global__ __launch_bounds__(256) void k_inproj(
    const u16* __restrict__ xb, const u16* __restrict__ WinT,
    const float* __restrict__ dt_bias, const float* __restrict__ A_log,
    u16* __restrict__ xbcdt, float* __restrict__ dAv) {
  __shared__ __align__(16) short sA[128 * 32];
  __shared__ __align__(16) short sB[128 * 32];
  const int tid = threadIdx.x;
  const int wave = tid >> 6, lane = tid & 63;
  const int m0 = blockIdx.y * 128, n0 = blockIdx.x * 128;
  const int wr = wave >> 1, wc = wave & 1;
  f32x4 acc[4][4] = {};

  const u16* gA[2]; const u16* gB[2]; int ldsOff[2];
#pragma unroll
  for (int q = 0; q < 2; ++q) {
    int G = wave * 128 + q * 64 + lane;
    int row = G >> 2, kc = G & 3;
    gA[q] = xb + (size_t)(m0 + row) * DM + kc * 8;
    gB[q] = WinT + (size_t)(n0 + row) * DM + kc * 8;
    ldsOff[q] = (wave * 128 + q * 64) * 8;
  }

  for (int k0 = 0; k0 < DM; k0 += 32) {
    if (k0) __syncthreads();
#pragma unroll
    for (int q = 0; q < 2; ++q) GLDS(gA[q] + k0, sA + ldsOff[q]);
#pragma unroll
    for (int q = 0; q < 2; ++q) GLDS(gB[q] + k0, sB + ldsOff[q]);
    __syncthreads();
    const int kb = (lane >> 4) * 8;
    s16x8 af[4], bf[4];
#pragma unroll
    for (int i = 0; i < 4; ++i)
      af[i] = *(const s16x8*)&sA[(wr * 64 + i * 16 + (lane & 15)) * 32 + kb];
#pragma unroll
    for (int j = 0; j < 4; ++j)
      bf[j] = *(const s16x8*)&sB[(wc * 64 + j * 16 + (lane & 15)) * 32 + kb];
#pragma unroll
    for (int i = 0; i < 4; ++i)
#pragma unroll
      for (int j = 0; j < 4; ++j)
        acc[i][j] = __builtin_amdgcn_mfma_f32_16x16x32_bf16(af[i], bf[j], acc[i][j], 0, 0, 0);
  }

  const int cl = lane & 15;
  const int row_base = m0 + wr * 64 + ((lane >> 4) << 2);
  if (n0 < 640) {
    const int col_base = n0 + wc * 64;
#pragma unroll
    for (int i = 0; i < 4; ++i)
#pragma unroll
      for (int r = 0; r < 4; ++r) {
        int row = row_base + i * 16 + r;
#pragma unroll
        for (int j = 0; j < 4; ++j)
          xbcdt[(size_t)row * XBW + col_base + j * 16 + cl] = f2bf(acc[i][j][r]);
      }
  } else if (wc == 0 && cl < 8) {
    const float nAe = -expf(A_log[cl]);
    const float db = dt_bias[cl];
#pragma unroll
    for (int i = 0; i < 4; ++i)
#pragma unroll
      for (int r = 0; r < 4; ++r) {
        int row = row_base + i * 16 + r;
        dAv[(size_t)row * NH + cl] = softplusf(acc[i][0][r] + db) * nAe;
      }
  }
}

// ---------- Kernel 1b: Bt[b][s][l] = B_ssm (xbcdt cols 512..575) transposed --
__global__ __launch_bounds__(256) void k_bt(
    const u16* __restrict__ xbcdt, u16* __restrict__ Bt) {
  __shared__ u16 sT[64][72];           // [l][s], pad 72
  const int m0 = blockIdx.x * 64;
  const int b  = m0 >> 12;
  const int l0 = m0 & (L_N - 1);
  const int tid = threadIdx.x;
#pragma unroll
  for (int q = 0; q < 2; ++q) {
    int r = (tid >> 3) + q * 32, c8 = (tid & 7) * 8;
    u16x8 v = *(const u16x8*)&xbcdt[(size_t)(m0 + r) * XBW + DIN + c8];
#pragma unroll
    for (int jj = 0; jj < 8; ++jj) sT[r][c8 + jj] = v[jj];
  }
  __syncthreads();
#pragma unroll
  for (int q = 0; q < 2; ++q) {
    int s = (tid >> 3) + q * 32, lc8 = (tid & 7) * 8;
    u16x8 o;
#pragma unroll
    for (int jj = 0; jj < 8; ++jj) o[jj] = sT[lc8 + jj][s];
    *(u16x8*)&Bt[((size_t)(b * 64 + s)) * L_N + l0 + lc8] = o;
  }
}

// ---------- Kernel 2: MFMA KV-partials: KVp[chunk][bh][s][p] ----------
__global__ __launch_bounds__(256) void k_kv(
    const u16* __restrict__ xbcdt, const u16* __restrict__ Bt,
    const float* __restrict__ dAv, float* __restrict__ KVp) {
  const int bh = blockIdx.y;
  const int b = bh >> 3, h = bh & 7;
  const int l0 = blockIdx.x * (L_N / 4);   // 1024-l chunk
  const int tid = threadIdx.x;
  const int wave = tid >> 6, lane = tid & 63;
  const int wr = wave >> 1, wc = wave & 1;
  const int fr = lane & 15, fq = lane >> 4;
  __shared__ short sBt[64 * 36];   // [s][l-chunk32] pad 36
  __shared__ short sVt[64 * 36];   // [p][l-chunk32] (scaled by dA)
  f32x4 acc[2][2] = {};
  const int ts = tid >> 2, tlc = tid & 3;      // B staging
  const int tl = tid >> 3, tpg = tid & 7;      // V staging

  for (int ks = 0; ks < L_N / 4; ks += 32) {
    u16x8 vb = *(const u16x8*)&Bt[((size_t)(b * 64 + ts)) * L_N + l0 + ks + tlc * 8];
    const int gl = b * L_N + l0 + ks + tl;
    u16x8 vv = *(const u16x8*)&xbcdt[(size_t)gl * XBW + h * HD + tpg * 8];
    const float da = dAv[(size_t)gl * NH + h];
    __syncthreads();
    *(s16x4*)&sBt[ts * 36 + tlc * 8]     = *(s16x4*)&vb;
    *(s16x4*)&sBt[ts * 36 + tlc * 8 + 4] = *((s16x4*)&vb + 1);
#pragma unroll
    for (int jj = 0; jj < 8; ++jj)
      sVt[(tpg * 8 + jj) * 36 + tl] = (short)f2bf(bf2f(vv[jj]) * da);
    __syncthreads();
    s16x8 af[2], bf[2];
#pragma unroll
    for (int i = 0; i < 2; ++i)
      af[i] = ld_frag2(&sBt[(wr * 32 + i * 16 + fr) * 36 + fq * 8]);
#pragma unroll
    for (int j = 0; j < 2; ++j)
      bf[j] = ld_frag2(&sVt[(wc * 32 + j * 16 + fr) * 36 + fq * 8]);
#pragma unroll
    for (int i = 0; i < 2; ++i)
#pragma unroll
      for (int j = 0; j < 2; ++j)
        acc[i][j] = __builtin_amdgcn_mfma_f32_16x16x32_bf16(af[i], bf[j], acc[i][j], 0, 0, 0);
  }
  float* dst = KVp + ((size_t)(blockIdx.x * 256 + bh)) * 4096;
#pragma unroll
  for (int i = 0; i < 2; ++i)
#pragma unroll
    for (int j = 0; j < 2; ++j)
#pragma unroll
      for (int r = 0; r < 4; ++r) {
        int s = wr * 32 + i * 16 + fq * 4 + r;
        int p = wc * 32 + j * 16 + fr;
        dst[s * 64 + p] = acc[i][j][r];
      }
}

// ---------- Kernel 3: MFMA y = C @ KV + V*D, bf16 in-place over V ----------
// grid (NH, M_N/128); A = C rows (xbcdt cols 576..639), B = KV^T [p][s]
__global__ __launch_bounds__(256) void k_ygemm(
    u16* __restrict__ xb, const float* __restrict__ KVp,
    const float* __restrict__ Dp) {
  __shared__ __align__(16) short sC[128 * 72];  // [row][s], pad 72
  __shared__ __align__(16) short sKt[64 * 76];  // [p][s], stride 76 (s runs 0..63!)
  const int h = blockIdx.x;
  const int m0 = blockIdx.y * 128;
  const int b = m0 >> 12;
  const int tid = threadIdx.x;
  const int wave = tid >> 6, lane = tid & 63;
  const int fr = lane & 15, fq = lane >> 4;

  // stage C: 128 rows x 64 s (1024 u16x8 loads)
#pragma unroll
  for (int q = 0; q < 4; ++q) {
    int idx = tid + q * 256;
    int row = idx >> 3, c8 = (idx & 7) * 8;
    u16x8 v = *(const u16x8*)&xb[(size_t)(m0 + row) * XBW + DIN + DS + c8];
    *(u16x8*)&sC[row * 72 + c8] = v;
  }
  // stage KV^T: sum 4 partials, transpose, cvt bf16
  {
    const float* kvb = KVp + (size_t)(b * NH + h) * 4096;
#pragma unroll
    for (int q = 0; q < 4; ++q) {
      int idx = tid + q * 256;          // 1024 float4s
      int s = idx >> 4, pg = idx & 15;
      float4 v0 = *(const float4*)(kvb + s * 64 + pg * 4);
      float4 v1 = *(const float4*)(kvb + 1048576 + s * 64 + pg * 4);
      float4 v2 = *(const float4*)(kvb + 2097152 + s * 64 + pg * 4);
      float4 v3 = *(const float4*)(kvb + 3145728 + s * 64 + pg * 4);
      sKt[(pg * 4 + 0) * 76 + s] = (short)f2bf(v0.x + v1.x + v2.x + v3.x);
      sKt[(pg * 4 + 1) * 76 + s] = (short)f2bf(v0.y + v1.y + v2.y + v3.y);
      sKt[(pg * 4 + 2) * 76 + s] = (short)f2bf(v0.z + v1.z + v2.z + v3.z);
      sKt[(pg * 4 + 3) * 76 + s] = (short)f2bf(v0.w + v1.w + v2.w + v3.w);
    }
  }
  __syncthreads();
  f32x4 acc[2][4] = {};
#pragma unroll
  for (int kk = 0; kk < 2; ++kk) {
    s16x8 af[2], bf[4];
#pragma unroll
    for (int i = 0; i < 2; ++i)
      af[i] = *(const s16x8*)&sC[(wave * 32 + i * 16 + fr) * 72 + kk * 32 + fq * 8];
#pragma unroll
    for (int j = 0; j < 4; ++j)
      bf[j] = ld_frag2(&sKt[(j * 16 + fr) * 76 + kk * 32 + fq * 8]);
#pragma unroll
    for (int i = 0; i < 2; ++i)
#pragma unroll
      for (int j = 0; j < 4; ++j)
        acc[i][j] = __builtin_amdgcn_mfma_f32_16x16x32_bf16(af[i], bf[j], acc[i][j], 0, 0, 0);
  }
  const float dscale = Dp[h];
#pragma unroll
  for (int i = 0; i < 2; ++i)
#pragma unroll
    for (int r = 0; r < 4; ++r) {
      int row = m0 + wave * 32 + i * 16 + fq * 4 + r;
#pragma unroll
      for (int j = 0; j < 4; ++j) {
        size_t idx = (size_t)row * XBW + h * HD + j * 16 + fr;
        float v = bf2f(xb[idx]);
        xb[idx] = f2bf(acc[i][j][r] + v * dscale);
      }
    }
}

// ---------- Kernel 4: fused row-stats + LayerNorm, in place (bf16) ----------
__global__ __launch_bounds__(256) void k_statsln(
    u16* __restrict__ xb, const float* __restrict__ g, const float* __restrict__ bt) {
  const int w = threadIdx.x >> 6, lane = threadIdx.x & 63;
  const size_t row = (size_t)blockIdx.x * 4 + w;
  u16* yr = xb + row * XBW;
  u16x8 v = *(const u16x8*)(yr + lane * 8);
  float f[8];
  float s = 0.f, q = 0.f;
#pragma unroll
  for (int j = 0; j < 8; ++j) {
    f[j] = bf2f(v[j]);
    s += f[j]; q += f[j] * f[j];
  }
#pragma unroll
  for (int off = 1; off < 64; off <<= 1) {
    s += __shfl_xor(s, off);
    q += __shfl_xor(q, off);
  }
  const float mu = s / DIN;
  const float rstd = rsqrtf(q / DIN - mu * mu + 1e-5f);
  float4 g0 = *reinterpret_cast<const float4*>(g + lane * 8);
  float4 g1 = *reinterpret_cast<const float4*>(g + lane * 8 + 4);
  float4 b0 = *reinterpret_cast<const float4*>(bt + lane * 8);
  float4 b1 = *reinterpret_cast<const float4*>(bt + lane * 8 + 4);
  float gg[8] = {g0.x, g0.y, g0.z, g0.w, g1.x, g1.y, g1.z, g1.w};
  float bb[8] = {b0.x, b0.y, b0.z, b0.w, b1.x, b1.y, b1.z, b1.w};
  u16x8 o;
#pragma unroll
  for (int j = 0; j < 8; ++j)
    o[j] = f2bf((f[j] - mu) * rstd * gg[j] + bb[j]);
  *(u16x8*)(yr + lane * 8) = o;
}

// ---------- Kernel 5: bf16 MFMA out-proj: [M,512]@[512,256] ----------
__global__ __launch_bounds__(256) void k_outgemm(
    const u16* __restrict__ xbcdt, const u16* __restrict__ WoT,
    float* __restrict__ out) {
  __shared__ __align__(16) short sA[128 * 32];
  __shared__ __align__(16) short sB[128 * 32];
  const int tid = threadIdx.x;
  const int wave = tid >> 6, lane = tid & 63;
  const int m0 = blockIdx.y * 128, n0 = blockIdx.x * 128;
  const int wr = wave >> 1, wc = wave & 1;
  f32x4 acc[4][4] = {};

  const u16* gA[2]; const u16* gB[2]; int ldsOff[2];
#pragma unroll
  for (int q = 0; q < 2; ++q) {
    int G = wave * 128 + q * 64 + lane;
    int row = G >> 2, kc = G & 3;
    gA[q] = xbcdt + (size_t)(m0 + row) * XBW + kc * 8;
    gB[q] = WoT + (size_t)(n0 + row) * DIN + kc * 8;
    ldsOff[q] = (wave * 128 + q * 64) * 8;
  }

  for (int k0 = 0; k0 < DIN; k0 += 32) {
    if (k0) __syncthreads();
#pragma unroll
    for (int q = 0; q < 2; ++q) GLDS(gA[q] + k0, sA + ldsOff[q]);
#pragma unroll
    for (int q = 0; q < 2; ++q) GLDS(gB[q] + k0, sB + ldsOff[q]);
    __syncthreads();
    const int kb = (lane >> 4) * 8;
    s16x8 af[4], bf[4];
#pragma unroll
    for (int i = 0; i < 4; ++i)
      af[i] = *(const s16x8*)&sA[(wr * 64 + i * 16 + (lane & 15)) * 32 + kb];
#pragma unroll
    for (int j = 0; j < 4; ++j)
      bf[j] = *(const s16x8*)&sB[(wc * 64 + j * 16 + (lane & 15)) * 32 + kb];
#pragma unroll
    for (int i = 0; i < 4; ++i)
#pragma unroll
      for (int j = 0; j < 4; ++j)
        acc[i][j] = __builtin_amdgcn_mfma_f32_16x16x32_bf16(af[i], bf[j], acc[i][j], 0, 0, 0);
  }

  const int cl = lane & 15;
  const int row_base = m0 + wr * 64 + ((lane >> 4) << 2);
  const int col_base = n0 + wc * 64;
#pragma unroll
  for (int i = 0; i < 4; ++i)
#pragma unroll
    for (int r = 0; r < 4; ++r) {
      int row = row_base + i * 16 + r;
#pragma unroll
      for (int j = 0; j < 4; ++j)
        out[(size_t)row * DM + col_base + j * 16 + cl] = acc[i][j][r];
    }
}

extern "C" void kernel_launch(void* const* d_in, const int* in_sizes, int n_in,
                              void* d_out, int out_size, void* d_ws, size_t ws_size,
                              hipStream_t stream) {
  const float* x       = (const float*)d_in[0];
  const float* W_in    = (const float*)d_in[1];
  const float* dt_bias = (const float*)d_in[2];
  const float* A_log   = (const float*)d_in[3];
  const float* D_param = (const float*)d_in[4];
  const float* gamma   = (const float*)d_in[5];
  const float* beta    = (const float*)d_in[6];
  const float* W_out   = (const float*)d_in[7];
  float* out = (float*)d_out;

  u16* ws    = (u16*)d_ws;
  u16* xb    = ws;                                    // M*256 bf16
  u16* WinT  = xb + (size_t)M_N * DM;                 // 768*256
  u16* WoT   = WinT + 768L * 256;                     // 256*512
  u16* xbcdt = WoT + 256L * 512;                      // M*640 bf16
  u16* Bt    = xbcdt + (size_t)M_N * XBW;             // 32*64*4096 bf16
  float* dAv = (float*)(Bt + (size_t)B_N * 64 * L_N); // M*8 fp32
  float* KVp = dAv + (size_t)M_N * NH;                // 4*256*4096 fp32

  k_cvt    <<<4096, 256, 0, stream>>>(x, W_in, W_out, xb, WinT, WoT);
  k_inproj <<<dim3(6, M_N / 128), 256, 0, stream>>>(xb, WinT, dt_bias, A_log, xbcdt, dAv);
  k_bt     <<<M_N / 64, 256, 0, stream>>>(xbcdt, Bt);
  k_kv     <<<dim3(4, B_N * NH), 256, 0, stream>>>(xbcdt, Bt, dAv, KVp);
  k_ygemm  <<<dim3(NH, M_N / 128), 256, 0, stream>>>(xbcdt, KVp, D_param);
  k_statsln<<<M_N / 4, 256, 0, stream>>>(xbcdt, gamma, beta);
  k_outgemm<<<dim3(DM / 128, M_N / 128), 256, 0, stream>>>(xbcdt, WoT, out);
}